// Round 1
// baseline (1392.545 us; speedup 1.0000x reference)
//
#include <hip/hip_runtime.h>

// Problem: T=1024, B=256, D=64, H=128, all fp32.
// ws layout: Z = (float*)d_ws, T*B*H floats (134,217,728 B).
//   k_feat_z writes Z[t*B+b][j] = input projection z_t (both biases folded).
//   k_scan   (256 WGs, one per batch elem) runs the recurrence; at step t it
//            consumes z_t and overwrites that slot with h_{t+1}. So after the
//            scan, Z[(t-1)*B + b] == h_t (pre-update state for step t).
//   k_out    computes y_t = tanh(h_t W_h^T + b_h) W_g^T + b_g; t==0 uses h=0.

#define T_SEQ 1024
#define B_SZ  256
#define D_IN  64
#define H_DIM 128

__device__ __forceinline__ float fast_tanh(float x) {
  // tanh(x) = sign(x) * (1 - e^{-2|x|}) / (1 + e^{-2|x|}); exp via v_exp_f32.
  float ax = __builtin_fabsf(x);
  float e  = __builtin_amdgcn_exp2f(ax * -2.8853900817779268f); // -2*log2(e)
  float r  = (1.0f - e) * __builtin_amdgcn_rcpf(1.0f + e);
  return __builtin_copysignf(r, x);
}

// ---------------------------------------------------------------------------
// Kernel 1: z = tanh(x @ Wx^T + bx) @ Wih^T + (bih + bhh)
// 64 rows/block, 256 threads. LDS (64KB): transposed operands for
// conflict-light b128 reads; Wih staged in 4 K-chunks of 32 to fit 64KB.
// Thread tile: 4 rows x 8 cols (rg = tid>>4, cg = tid&15).
// ---------------------------------------------------------------------------
__global__ __launch_bounds__(256) void k_feat_z(
    const float* __restrict__ x,  const float* __restrict__ Wx,
    const float* __restrict__ bx, const float* __restrict__ Wih,
    const float* __restrict__ bih,const float* __restrict__ bhh,
    float* __restrict__ Z)
{
  __shared__ __align__(16) float lds[16384];          // exactly 64 KB
  float* xT    = lds;            // [64][68]   4352 f   (dead after phase A)
  float* WxT   = lds + 4352;     // [64][132]  8448 f   (dead after phase A)
  float* featT = lds;            // [128][68]  8704 f   (reuses xT/WxT region)
  float* WT    = lds + 9216;     // [32][132]  4224 f   (Wih K-chunk)
  float* bxs   = lds + 16128;    // [128]
  float* b2s   = lds + 16256;    // [128]

  const int tid = threadIdx.x;
  const int r0  = blockIdx.x * 64;
  const int rg  = tid >> 4;      // 0..15 -> rows rg*4 .. rg*4+3
  const int cg  = tid & 15;      // 0..15 -> cols cg*8 .. cg*8+7

  if (tid < 128) { bxs[tid] = bx[tid]; b2s[tid] = bih[tid] + bhh[tid]; }

  { // stage x tile transposed: xT[d][r]
    const float4* xg = (const float4*)(x + (long)r0 * D_IN);
#pragma unroll
    for (int k = 0; k < 4; ++k) {
      int l = tid + k * 256;                 // 1024 float4 = 64x64
      float4 v = xg[l];
      int r = l >> 4, d0 = (l & 15) * 4;
      xT[(d0+0)*68 + r] = v.x; xT[(d0+1)*68 + r] = v.y;
      xT[(d0+2)*68 + r] = v.z; xT[(d0+3)*68 + r] = v.w;
    }
  }
  { // stage WxT[d][j] from Wx[j][d] (Wx is [128][64])
    const float4* wg = (const float4*)Wx;
#pragma unroll
    for (int k = 0; k < 8; ++k) {
      int l = tid + k * 256;                 // 2048 float4 = 128x64
      float4 v = wg[l];
      int j = l >> 4, d0 = (l & 15) * 4;
      WxT[(d0+0)*132 + j] = v.x; WxT[(d0+1)*132 + j] = v.y;
      WxT[(d0+2)*132 + j] = v.z; WxT[(d0+3)*132 + j] = v.w;
    }
  }
  __syncthreads();

  // ---- phase A: feat = x @ Wx^T (K = 64) ----
  float acc[4][8];
#pragma unroll
  for (int i = 0; i < 4; ++i)
#pragma unroll
    for (int c = 0; c < 8; ++c) acc[i][c] = 0.f;

  for (int d = 0; d < 64; ++d) {
    float4 xv = *(const float4*)&xT[d*68 + rg*4];
    float4 wa = *(const float4*)&WxT[d*132 + cg*8];
    float4 wb = *(const float4*)&WxT[d*132 + cg*8 + 4];
    float xr[4] = {xv.x, xv.y, xv.z, xv.w};
    float wc[8] = {wa.x, wa.y, wa.z, wa.w, wb.x, wb.y, wb.z, wb.w};
#pragma unroll
    for (int i = 0; i < 4; ++i)
#pragma unroll
      for (int c = 0; c < 8; ++c)
        acc[i][c] = fmaf(xr[i], wc[c], acc[i][c]);
  }
  __syncthreads();                       // xT/WxT reads done before overwrite

  // tanh + bias -> featT[j][r]
#pragma unroll
  for (int c = 0; c < 8; ++c) {
    float bv = bxs[cg*8 + c];
#pragma unroll
    for (int i = 0; i < 4; ++i)
      featT[(cg*8+c)*68 + rg*4 + i] = fast_tanh(acc[i][c] + bv);
  }

  // ---- phase B: z = feat @ Wih^T (K = 128, 4 chunks of 32) ----
  float acc2[4][8];
#pragma unroll
  for (int i = 0; i < 4; ++i)
#pragma unroll
    for (int c = 0; c < 8; ++c) acc2[i][c] = 0.f;

  for (int jc = 0; jc < 4; ++jc) {
    __syncthreads();                     // featT written / prev chunk consumed
#pragma unroll
    for (int k = 0; k < 16; ++k) {
      int l = tid + k * 256;             // 4096 = 32x128
      int o = l >> 5, jl = l & 31;
      WT[jl*132 + o] = Wih[o*128 + jc*32 + jl];
    }
    __syncthreads();
    for (int jl = 0; jl < 32; ++jl) {
      float4 fv = *(const float4*)&featT[(jc*32+jl)*68 + rg*4];
      float4 wa = *(const float4*)&WT[jl*132 + cg*8];
      float4 wb = *(const float4*)&WT[jl*132 + cg*8 + 4];
      float fr[4] = {fv.x, fv.y, fv.z, fv.w};
      float wc[8] = {wa.x, wa.y, wa.z, wa.w, wb.x, wb.y, wb.z, wb.w};
#pragma unroll
      for (int i = 0; i < 4; ++i)
#pragma unroll
        for (int c = 0; c < 8; ++c)
          acc2[i][c] = fmaf(fr[i], wc[c], acc2[i][c]);
    }
  }

  // epilogue: + (bih+bhh), store
#pragma unroll
  for (int i = 0; i < 4; ++i) {
    long r = r0 + rg*4 + i;
    float4 o1, o2;
    o1.x = acc2[i][0] + b2s[cg*8+0]; o1.y = acc2[i][1] + b2s[cg*8+1];
    o1.z = acc2[i][2] + b2s[cg*8+2]; o1.w = acc2[i][3] + b2s[cg*8+3];
    o2.x = acc2[i][4] + b2s[cg*8+4]; o2.y = acc2[i][5] + b2s[cg*8+5];
    o2.z = acc2[i][6] + b2s[cg*8+6]; o2.w = acc2[i][7] + b2s[cg*8+7];
    *(float4*)&Z[r*128 + cg*8]     = o1;
    *(float4*)&Z[r*128 + cg*8 + 4] = o2;
  }
}

// ---------------------------------------------------------------------------
// Kernel 2: recurrence. One WG per batch element (grid=256), 256 threads.
// thread (j = tid&127, half = tid>>7) computes half the dot for output j;
// W_hh half-row lives in 16 float4 registers. z prefetched 4 steps deep.
// h_{t+1} overwrites Z[t] in place.
// ---------------------------------------------------------------------------
__global__ __launch_bounds__(256) void k_scan(const float* __restrict__ Whh,
                                              float* __restrict__ Z)
{
  __shared__ __align__(16) float h_lds[128];
  __shared__ float part[2][128];
  const int tid  = threadIdx.x;
  const int b    = blockIdx.x;
  const int j    = tid & 127;
  const int half = tid >> 7;

  float4 w[16];
  {
    const float4* wg = (const float4*)(Whh + j*128 + half*64);
#pragma unroll
    for (int m = 0; m < 16; ++m) w[m] = wg[m];
  }
  if (tid < 128) h_lds[tid] = 0.f;

  float* zp = Z + b*128 + j;            // stride per t: B*H = 32768
  float zbuf[4] = {0.f, 0.f, 0.f, 0.f};
  if (half == 0) {
#pragma unroll
    for (int i = 0; i < 4; ++i) zbuf[i] = zp[i * 32768];
  }
  __syncthreads();

  for (int t = 0; t < T_SEQ; ++t) {
    const float4* h4 = (const float4*)(h_lds + half*64);
    float a[4] = {0.f, 0.f, 0.f, 0.f};
#pragma unroll
    for (int m = 0; m < 16; ++m) {
      float4 hv = h4[m];
      float4 wv = w[m];
      a[m & 3] = fmaf(wv.x, hv.x,
                 fmaf(wv.y, hv.y,
                 fmaf(wv.z, hv.z,
                 fmaf(wv.w, hv.w, a[m & 3]))));
    }
    part[half][j] = (a[0] + a[1]) + (a[2] + a[3]);
    __syncthreads();
    if (half == 0) {
      float v = part[0][j] + part[1][j] + zbuf[0];
      float h = fast_tanh(v);
      h_lds[j] = h;                     // next state
      zp[t * 32768] = h;                // store h_{t+1} over consumed z_t
      zbuf[0] = zbuf[1]; zbuf[1] = zbuf[2]; zbuf[2] = zbuf[3];
      zbuf[3] = (t + 4 < T_SEQ) ? zp[(t + 4) * 32768] : 0.f;
    }
    __syncthreads();
  }
}

// ---------------------------------------------------------------------------
// Kernel 3: y = tanh(h @ Wh^T + bh) @ Wg^T + bg.
// Same tiling as kernel 1; h row for flat row r (= t*B+b) is zeros for t==0,
// else Z[r-256]. Phase A K-chunks Wh; phase B outputs 64 cols (4x4 tile).
// ---------------------------------------------------------------------------
__global__ __launch_bounds__(256) void k_out(
    const float* __restrict__ Zh, const float* __restrict__ Wh,
    const float* __restrict__ bh, const float* __restrict__ Wg,
    const float* __restrict__ bg, float* __restrict__ y)
{
  __shared__ __align__(16) float lds[16384];
  float* hT   = lds;            // [128][68] 8704 f
  float* mlpT = lds;            // reuse after phase A
  float* WT   = lds + 9216;     // [32][132] phase A / [32][68] phase B
  float* bhs  = lds + 16128;    // [128]
  float* bgs  = lds + 16256;    // [64]

  const int tid = threadIdx.x;
  const int r0  = blockIdx.x * 64;
  const int rg  = tid >> 4;
  const int cg  = tid & 15;
  const bool zero = (r0 < 256); // t == 0 block -> h = 0

  if (tid < 128) bhs[tid] = bh[tid];
  if (tid < 64)  bgs[tid] = bg[tid];

  { // stage hT[j][r]
    const float4* hg = (const float4*)(Zh + (long)(r0 - 256) * 128);
#pragma unroll
    for (int k = 0; k < 8; ++k) {
      int l = tid + k * 256;            // 2048 float4 = 64x128
      float4 v;
      if (zero) { v.x = v.y = v.z = v.w = 0.f; } else { v = hg[l]; }
      int r = l >> 5, j0 = (l & 31) * 4;
      hT[(j0+0)*68 + r] = v.x; hT[(j0+1)*68 + r] = v.y;
      hT[(j0+2)*68 + r] = v.z; hT[(j0+3)*68 + r] = v.w;
    }
  }

  // ---- phase A: m = h @ Wh^T (K = 128, 4 chunks) ----
  float acc[4][8];
#pragma unroll
  for (int i = 0; i < 4; ++i)
#pragma unroll
    for (int c = 0; c < 8; ++c) acc[i][c] = 0.f;

  for (int jc = 0; jc < 4; ++jc) {
    __syncthreads();
#pragma unroll
    for (int k = 0; k < 16; ++k) {
      int l = tid + k * 256;
      int o = l >> 5, jl = l & 31;
      WT[jl*132 + o] = Wh[o*128 + jc*32 + jl];
    }
    __syncthreads();
    for (int jl = 0; jl < 32; ++jl) {
      float4 hv = *(const float4*)&hT[(jc*32+jl)*68 + rg*4];
      float4 wa = *(const float4*)&WT[jl*132 + cg*8];
      float4 wb = *(const float4*)&WT[jl*132 + cg*8 + 4];
      float hr[4] = {hv.x, hv.y, hv.z, hv.w};
      float wc[8] = {wa.x, wa.y, wa.z, wa.w, wb.x, wb.y, wb.z, wb.w};
#pragma unroll
      for (int i = 0; i < 4; ++i)
#pragma unroll
        for (int c = 0; c < 8; ++c)
          acc[i][c] = fmaf(hr[i], wc[c], acc[i][c]);
    }
  }
  __syncthreads();                      // hT reads done before mlpT overwrite

#pragma unroll
  for (int c = 0; c < 8; ++c) {
    float bv = bhs[cg*8 + c];
#pragma unroll
    for (int i = 0; i < 4; ++i)
      mlpT[(cg*8+c)*68 + rg*4 + i] = fast_tanh(acc[i][c] + bv);
  }

  // ---- phase B: y = m @ Wg^T (64 out cols; thread tile 4x4) ----
  float acc2[4][4];
#pragma unroll
  for (int i = 0; i < 4; ++i)
#pragma unroll
    for (int c = 0; c < 4; ++c) acc2[i][c] = 0.f;

  for (int jc = 0; jc < 4; ++jc) {
    __syncthreads();
#pragma unroll
    for (int k = 0; k < 8; ++k) {
      int l = tid + k * 256;            // 2048 = 32x64
      int o = l >> 5, jl = l & 31;
      WT[jl*68 + o] = Wg[o*128 + jc*32 + jl];
    }
    __syncthreads();
    for (int jl = 0; jl < 32; ++jl) {
      float4 mv = *(const float4*)&mlpT[(jc*32+jl)*68 + rg*4];
      float4 wa = *(const float4*)&WT[jl*68 + cg*4];
      float mr[4] = {mv.x, mv.y, mv.z, mv.w};
      float wc[4] = {wa.x, wa.y, wa.z, wa.w};
#pragma unroll
      for (int i = 0; i < 4; ++i)
#pragma unroll
        for (int c = 0; c < 4; ++c)
          acc2[i][c] = fmaf(mr[i], wc[c], acc2[i][c]);
    }
  }

#pragma unroll
  for (int i = 0; i < 4; ++i) {
    long r = r0 + rg*4 + i;
    float4 o;
    o.x = acc2[i][0] + bgs[cg*4+0];
    o.y = acc2[i][1] + bgs[cg*4+1];
    o.z = acc2[i][2] + bgs[cg*4+2];
    o.w = acc2[i][3] + bgs[cg*4+3];
    *(float4*)&y[r*64 + cg*4] = o;
  }
}

extern "C" void kernel_launch(void* const* d_in, const int* in_sizes, int n_in,
                              void* d_out, int out_size, void* d_ws, size_t ws_size,
                              hipStream_t stream) {
  const float* x   = (const float*)d_in[0];
  const float* Wx  = (const float*)d_in[1];
  const float* bx  = (const float*)d_in[2];
  const float* Wih = (const float*)d_in[3];
  const float* bih = (const float*)d_in[4];
  const float* Whh = (const float*)d_in[5];
  const float* bhh = (const float*)d_in[6];
  const float* Wh  = (const float*)d_in[7];
  const float* bh  = (const float*)d_in[8];
  const float* Wg  = (const float*)d_in[9];
  const float* bg  = (const float*)d_in[10];
  float* Z = (float*)d_ws;              // needs T*B*H*4 = 134,217,728 B
  float* y = (float*)d_out;

  k_feat_z<<<(T_SEQ * B_SZ) / 64, 256, 0, stream>>>(x, Wx, bx, Wih, bih, bhh, Z);
  k_scan  <<<B_SZ,               256, 0, stream>>>(Whh, Z);
  k_out   <<<(T_SEQ * B_SZ) / 64, 256, 0, stream>>>(Z, Wh, bh, Wg, bg, y);
}

// Round 2
// 1051.492 us; speedup vs baseline: 1.3244x; 1.3244x over previous
//
#include <hip/hip_runtime.h>

// Problem: T=1024, B=256, D=64, H=128, all fp32.
// ws layout: Z = (float*)d_ws, T*B*H floats (134,217,728 B).
//   k_feat_z writes Z[t*B+b][j] = input projection z_t (both biases folded).
//   k_scan   (256 WGs, one per batch elem) runs the recurrence; at step t it
//            consumes z_t and overwrites that slot with h_{t+1}. So after the
//            scan, Z[(t-1)*B + b] == h_t (pre-update state for step t).
//   k_out    computes y_t = tanh(h_t W_h^T + b_h) W_g^T + b_g; t==0 uses h=0.

#define T_SEQ 1024
#define B_SZ  256
#define D_IN  64
#define H_DIM 128

__device__ __forceinline__ float fast_tanh(float x) {
  // tanh(x) = sign(x) * (1 - e^{-2|x|}) / (1 + e^{-2|x|}); exp via v_exp_f32.
  float ax = __builtin_fabsf(x);
  float e  = __builtin_amdgcn_exp2f(ax * -2.8853900817779268f); // -2*log2(e)
  float r  = (1.0f - e) * __builtin_amdgcn_rcpf(1.0f + e);
  return __builtin_copysignf(r, x);
}

// lane-xor adds: xor1/xor2 via DPP quad_perm (VALU pipe), xor4 via ds_swizzle
__device__ __forceinline__ float add_xor1(float x) {
  int v = __builtin_amdgcn_mov_dpp(__float_as_int(x), 0xB1, 0xF, 0xF, true);
  return x + __int_as_float(v);
}
__device__ __forceinline__ float add_xor2(float x) {
  int v = __builtin_amdgcn_mov_dpp(__float_as_int(x), 0x4E, 0xF, 0xF, true);
  return x + __int_as_float(v);
}
__device__ __forceinline__ float add_xor4(float x) {
  // BitMode swizzle: offset = (xor<<10)|(or<<5)|and = (4<<10)|31 = 0x101F
  int v = __builtin_amdgcn_ds_swizzle(__float_as_int(x), 0x101F);
  return x + __int_as_float(v);
}

__device__ __forceinline__ float dot4(float4 w, float4 h) {
  return fmaf(w.x, h.x, fmaf(w.y, h.y, fmaf(w.z, h.z, w.w * h.w)));
}

// ---------------------------------------------------------------------------
// Kernel 1: z = tanh(x @ Wx^T + bx) @ Wih^T + (bih + bhh)
// 64 rows/block, 256 threads. (unchanged from R1)
// ---------------------------------------------------------------------------
__global__ __launch_bounds__(256) void k_feat_z(
    const float* __restrict__ x,  const float* __restrict__ Wx,
    const float* __restrict__ bx, const float* __restrict__ Wih,
    const float* __restrict__ bih,const float* __restrict__ bhh,
    float* __restrict__ Z)
{
  __shared__ __align__(16) float lds[16384];          // exactly 64 KB
  float* xT    = lds;            // [64][68]   4352 f   (dead after phase A)
  float* WxT   = lds + 4352;     // [64][132]  8448 f   (dead after phase A)
  float* featT = lds;            // [128][68]  8704 f   (reuses xT/WxT region)
  float* WT    = lds + 9216;     // [32][132]  4224 f   (Wih K-chunk)
  float* bxs   = lds + 16128;    // [128]
  float* b2s   = lds + 16256;    // [128]

  const int tid = threadIdx.x;
  const int r0  = blockIdx.x * 64;
  const int rg  = tid >> 4;      // 0..15 -> rows rg*4 .. rg*4+3
  const int cg  = tid & 15;      // 0..15 -> cols cg*8 .. cg*8+7

  if (tid < 128) { bxs[tid] = bx[tid]; b2s[tid] = bih[tid] + bhh[tid]; }

  { // stage x tile transposed: xT[d][r]
    const float4* xg = (const float4*)(x + (long)r0 * D_IN);
#pragma unroll
    for (int k = 0; k < 4; ++k) {
      int l = tid + k * 256;                 // 1024 float4 = 64x64
      float4 v = xg[l];
      int r = l >> 4, d0 = (l & 15) * 4;
      xT[(d0+0)*68 + r] = v.x; xT[(d0+1)*68 + r] = v.y;
      xT[(d0+2)*68 + r] = v.z; xT[(d0+3)*68 + r] = v.w;
    }
  }
  { // stage WxT[d][j] from Wx[j][d] (Wx is [128][64])
    const float4* wg = (const float4*)Wx;
#pragma unroll
    for (int k = 0; k < 8; ++k) {
      int l = tid + k * 256;                 // 2048 float4 = 128x64
      float4 v = wg[l];
      int j = l >> 4, d0 = (l & 15) * 4;
      WxT[(d0+0)*132 + j] = v.x; WxT[(d0+1)*132 + j] = v.y;
      WxT[(d0+2)*132 + j] = v.z; WxT[(d0+3)*132 + j] = v.w;
    }
  }
  __syncthreads();

  // ---- phase A: feat = x @ Wx^T (K = 64) ----
  float acc[4][8];
#pragma unroll
  for (int i = 0; i < 4; ++i)
#pragma unroll
    for (int c = 0; c < 8; ++c) acc[i][c] = 0.f;

  for (int d = 0; d < 64; ++d) {
    float4 xv = *(const float4*)&xT[d*68 + rg*4];
    float4 wa = *(const float4*)&WxT[d*132 + cg*8];
    float4 wb = *(const float4*)&WxT[d*132 + cg*8 + 4];
    float xr[4] = {xv.x, xv.y, xv.z, xv.w};
    float wc[8] = {wa.x, wa.y, wa.z, wa.w, wb.x, wb.y, wb.z, wb.w};
#pragma unroll
    for (int i = 0; i < 4; ++i)
#pragma unroll
      for (int c = 0; c < 8; ++c)
        acc[i][c] = fmaf(xr[i], wc[c], acc[i][c]);
  }
  __syncthreads();                       // xT/WxT reads done before overwrite

  // tanh + bias -> featT[j][r]
#pragma unroll
  for (int c = 0; c < 8; ++c) {
    float bv = bxs[cg*8 + c];
#pragma unroll
    for (int i = 0; i < 4; ++i)
      featT[(cg*8+c)*68 + rg*4 + i] = fast_tanh(acc[i][c] + bv);
  }

  // ---- phase B: z = feat @ Wih^T (K = 128, 4 chunks of 32) ----
  float acc2[4][8];
#pragma unroll
  for (int i = 0; i < 4; ++i)
#pragma unroll
    for (int c = 0; c < 8; ++c) acc2[i][c] = 0.f;

  for (int jc = 0; jc < 4; ++jc) {
    __syncthreads();                     // featT written / prev chunk consumed
#pragma unroll
    for (int k = 0; k < 16; ++k) {
      int l = tid + k * 256;             // 4096 = 32x128
      int o = l >> 5, jl = l & 31;
      WT[jl*132 + o] = Wih[o*128 + jc*32 + jl];
    }
    __syncthreads();
    for (int jl = 0; jl < 32; ++jl) {
      float4 fv = *(const float4*)&featT[(jc*32+jl)*68 + rg*4];
      float4 wa = *(const float4*)&WT[jl*132 + cg*8];
      float4 wb = *(const float4*)&WT[jl*132 + cg*8 + 4];
      float fr[4] = {fv.x, fv.y, fv.z, fv.w};
      float wc[8] = {wa.x, wa.y, wa.z, wa.w, wb.x, wb.y, wb.z, wb.w};
#pragma unroll
      for (int i = 0; i < 4; ++i)
#pragma unroll
        for (int c = 0; c < 8; ++c)
          acc2[i][c] = fmaf(fr[i], wc[c], acc2[i][c]);
    }
  }

  // epilogue: + (bih+bhh), store
#pragma unroll
  for (int i = 0; i < 4; ++i) {
    long r = r0 + rg*4 + i;
    float4 o1, o2;
    o1.x = acc2[i][0] + b2s[cg*8+0]; o1.y = acc2[i][1] + b2s[cg*8+1];
    o1.z = acc2[i][2] + b2s[cg*8+2]; o1.w = acc2[i][3] + b2s[cg*8+3];
    o2.x = acc2[i][4] + b2s[cg*8+4]; o2.y = acc2[i][5] + b2s[cg*8+5];
    o2.z = acc2[i][6] + b2s[cg*8+6]; o2.w = acc2[i][7] + b2s[cg*8+7];
    *(float4*)&Z[r*128 + cg*8]     = o1;
    *(float4*)&Z[r*128 + cg*8 + 4] = o2;
  }
}

// ---------------------------------------------------------------------------
// Kernel 2 (REWRITTEN): recurrence. One WG (256 thr) per batch elem.
// Thread (jg=tid>>3, ks=tid&7) computes outputs j in {jg,jg+32,jg+64,jg+96}
// over k in [ks*16, ks*16+16): 4x ds_read_b128 of h (4x less LDS traffic than
// R1), 64 fma, then 8-way K-reduction IN-REGISTER via DPP xor1/xor2 +
// ds_swizzle xor4 (no part[] LDS round-trip). h double-buffered in LDS ->
// ONE barrier per step. z prefetched 8 deep with modulo indexing (8x unroll).
// ---------------------------------------------------------------------------
__global__ __launch_bounds__(256) void k_scan(const float* __restrict__ Whh,
                                              float* __restrict__ Z)
{
  __shared__ __align__(16) float hbuf[2][128];
  const int tid = threadIdx.x;
  const int b   = blockIdx.x;
  const int jg  = tid >> 3;      // 0..31
  const int ks  = tid & 7;       // 0..7  (K-split lane group, contiguous lanes)
  const int k0  = ks * 16;

  // weights: W[j][k] for j = jg + r*32, k in [k0, k0+16)  -> 64 VGPRs
  float4 w[4][4];
#pragma unroll
  for (int r = 0; r < 4; ++r) {
    const float4* wg = (const float4*)(Whh + (jg + r*32)*H_DIM + k0);
#pragma unroll
    for (int m = 0; m < 4; ++m) w[r][m] = wg[m];
  }

  if (tid < 128) { hbuf[0][tid] = 0.f; }

  const bool writer = (ks < 4);
  const int  j_out  = jg + ks*32;            // valid for writer lanes
  float* zp = Z + b*H_DIM + j_out;           // stride per t: B*H = 32768

  float zbuf[8];
#pragma unroll
  for (int i = 0; i < 8; ++i) zbuf[i] = writer ? zp[i * 32768] : 0.f;

  __syncthreads();

  for (int tb = 0; tb < T_SEQ; tb += 8) {
#pragma unroll
    for (int u = 0; u < 8; ++u) {
      const int t = tb + u;
      const float* h = hbuf[t & 1];
      float4 h0 = *(const float4*)&h[k0];
      float4 h1 = *(const float4*)&h[k0 + 4];
      float4 h2 = *(const float4*)&h[k0 + 8];
      float4 h3 = *(const float4*)&h[k0 + 12];

      float a[4];
#pragma unroll
      for (int r = 0; r < 4; ++r) {
        float p0 = dot4(w[r][0], h0);
        float p1 = dot4(w[r][1], h1);
        float p2 = dot4(w[r][2], h2);
        float p3 = dot4(w[r][3], h3);
        a[r] = (p0 + p1) + (p2 + p3);
      }
      // butterfly over ks (lanes jg*8 .. jg*8+7)
#pragma unroll
      for (int r = 0; r < 4; ++r) {
        a[r] = add_xor1(a[r]);
        a[r] = add_xor2(a[r]);
        a[r] = add_xor4(a[r]);
      }
      if (writer) {
        float v  = a[ks] + zbuf[u];
        float hn = fast_tanh(v);
        hbuf[(t & 1) ^ 1][j_out] = hn;       // next state
        zp[t * 32768] = hn;                  // h_{t+1} over consumed z_t
        zbuf[u] = (t + 8 < T_SEQ) ? zp[(t + 8) * 32768] : 0.f;
      }
      __syncthreads();
    }
  }
}

// ---------------------------------------------------------------------------
// Kernel 3: y = tanh(h @ Wh^T + bh) @ Wg^T + bg.  (unchanged from R1)
// ---------------------------------------------------------------------------
__global__ __launch_bounds__(256) void k_out(
    const float* __restrict__ Zh, const float* __restrict__ Wh,
    const float* __restrict__ bh, const float* __restrict__ Wg,
    const float* __restrict__ bg, float* __restrict__ y)
{
  __shared__ __align__(16) float lds[16384];
  float* hT   = lds;            // [128][68] 8704 f
  float* mlpT = lds;            // reuse after phase A
  float* WT   = lds + 9216;     // [32][132] phase A / [32][68] phase B
  float* bhs  = lds + 16128;    // [128]
  float* bgs  = lds + 16256;    // [64]

  const int tid = threadIdx.x;
  const int r0  = blockIdx.x * 64;
  const int rg  = tid >> 4;
  const int cg  = tid & 15;
  const bool zero = (r0 < 256); // t == 0 block -> h = 0

  if (tid < 128) bhs[tid] = bh[tid];
  if (tid < 64)  bgs[tid] = bg[tid];

  { // stage hT[j][r]
    const float4* hg = (const float4*)(Zh + (long)(r0 - 256) * 128);
#pragma unroll
    for (int k = 0; k < 8; ++k) {
      int l = tid + k * 256;            // 2048 float4 = 64x128
      float4 v;
      if (zero) { v.x = v.y = v.z = v.w = 0.f; } else { v = hg[l]; }
      int r = l >> 5, j0 = (l & 31) * 4;
      hT[(j0+0)*68 + r] = v.x; hT[(j0+1)*68 + r] = v.y;
      hT[(j0+2)*68 + r] = v.z; hT[(j0+3)*68 + r] = v.w;
    }
  }

  // ---- phase A: m = h @ Wh^T (K = 128, 4 chunks) ----
  float acc[4][8];
#pragma unroll
  for (int i = 0; i < 4; ++i)
#pragma unroll
    for (int c = 0; c < 8; ++c) acc[i][c] = 0.f;

  for (int jc = 0; jc < 4; ++jc) {
    __syncthreads();
#pragma unroll
    for (int k = 0; k < 16; ++k) {
      int l = tid + k * 256;
      int o = l >> 5, jl = l & 31;
      WT[jl*132 + o] = Wh[o*128 + jc*32 + jl];
    }
    __syncthreads();
    for (int jl = 0; jl < 32; ++jl) {
      float4 hv = *(const float4*)&hT[(jc*32+jl)*68 + rg*4];
      float4 wa = *(const float4*)&WT[jl*132 + cg*8];
      float4 wb = *(const float4*)&WT[jl*132 + cg*8 + 4];
      float hr[4] = {hv.x, hv.y, hv.z, hv.w};
      float wc[8] = {wa.x, wa.y, wa.z, wa.w, wb.x, wb.y, wb.z, wb.w};
#pragma unroll
      for (int i = 0; i < 4; ++i)
#pragma unroll
        for (int c = 0; c < 8; ++c)
          acc[i][c] = fmaf(hr[i], wc[c], acc[i][c]);
    }
  }
  __syncthreads();                      // hT reads done before mlpT overwrite

#pragma unroll
  for (int c = 0; c < 8; ++c) {
    float bv = bhs[cg*8 + c];
#pragma unroll
    for (int i = 0; i < 4; ++i)
      mlpT[(cg*8+c)*68 + rg*4 + i] = fast_tanh(acc[i][c] + bv);
  }

  // ---- phase B: y = m @ Wg^T (64 out cols; thread tile 4x4) ----
  float acc2[4][4];
#pragma unroll
  for (int i = 0; i < 4; ++i)
#pragma unroll
    for (int c = 0; c < 4; ++c) acc2[i][c] = 0.f;

  for (int jc = 0; jc < 4; ++jc) {
    __syncthreads();
#pragma unroll
    for (int k = 0; k < 8; ++k) {
      int l = tid + k * 256;            // 2048 = 32x64
      int o = l >> 5, jl = l & 31;
      WT[jl*68 + o] = Wg[o*128 + jc*32 + jl];
    }
    __syncthreads();
    for (int jl = 0; jl < 32; ++jl) {
      float4 mv = *(const float4*)&mlpT[(jc*32+jl)*68 + rg*4];
      float4 wa = *(const float4*)&WT[jl*68 + cg*4];
      float mr[4] = {mv.x, mv.y, mv.z, mv.w};
      float wc[4] = {wa.x, wa.y, wa.z, wa.w};
#pragma unroll
      for (int i = 0; i < 4; ++i)
#pragma unroll
        for (int c = 0; c < 4; ++c)
          acc2[i][c] = fmaf(mr[i], wc[c], acc2[i][c]);
    }
  }

#pragma unroll
  for (int i = 0; i < 4; ++i) {
    long r = r0 + rg*4 + i;
    float4 o;
    o.x = acc2[i][0] + bgs[cg*4+0];
    o.y = acc2[i][1] + bgs[cg*4+1];
    o.z = acc2[i][2] + bgs[cg*4+2];
    o.w = acc2[i][3] + bgs[cg*4+3];
    *(float4*)&y[r*64 + cg*4] = o;
  }
}

extern "C" void kernel_launch(void* const* d_in, const int* in_sizes, int n_in,
                              void* d_out, int out_size, void* d_ws, size_t ws_size,
                              hipStream_t stream) {
  const float* x   = (const float*)d_in[0];
  const float* Wx  = (const float*)d_in[1];
  const float* bx  = (const float*)d_in[2];
  const float* Wih = (const float*)d_in[3];
  const float* bih = (const float*)d_in[4];
  const float* Whh = (const float*)d_in[5];
  const float* bhh = (const float*)d_in[6];
  const float* Wh  = (const float*)d_in[7];
  const float* bh  = (const float*)d_in[8];
  const float* Wg  = (const float*)d_in[9];
  const float* bg  = (const float*)d_in[10];
  float* Z = (float*)d_ws;              // needs T*B*H*4 = 134,217,728 B
  float* y = (float*)d_out;

  k_feat_z<<<(T_SEQ * B_SZ) / 64, 256, 0, stream>>>(x, Wx, bx, Wih, bih, bhh, Z);
  k_scan  <<<B_SZ,               256, 0, stream>>>(Whh, Z);
  k_out   <<<(T_SEQ * B_SZ) / 64, 256, 0, stream>>>(Z, Wh, bh, Wg, bg, y);
}

// Round 3
// 783.055 us; speedup vs baseline: 1.7783x; 1.3428x over previous
//
#include <hip/hip_runtime.h>

// T=1024, B=256, D=64, H=128, fp32 in/out.
// Z = d_ws (T*B*H fp32): k_feat_z writes z_t; k_scan overwrites slot t with
// h_{t+1} (so slot r-256 holds the pre-update h for flat row r); k_out_mfma
// computes y = tanh(h Wh^T + bh) Wg^T + bg in bf16 MFMA (fp32 accumulate).

#define T_SEQ 1024
#define B_SZ  256
#define D_IN  64
#define H_DIM 128

typedef __attribute__((ext_vector_type(8))) short short8;
typedef __attribute__((ext_vector_type(4))) short short4v;
typedef __attribute__((ext_vector_type(4))) float f32x4;

__device__ __forceinline__ float fast_tanh(float x) {
  float ax = __builtin_fabsf(x);
  float e  = __builtin_amdgcn_exp2f(ax * -2.8853900817779268f); // -2*log2(e)
  float r  = (1.0f - e) * __builtin_amdgcn_rcpf(1.0f + e);
  return __builtin_copysignf(r, x);
}

// barrier that waits ONLY lgkmcnt (LDS) — avoids __syncthreads' vmcnt(0)
// drain of in-flight global loads/stores. imm: vm=63, exp=7, lgkm=0 -> 0xC07F
__device__ __forceinline__ void barrier_lds_only() {
  __asm__ __volatile__("" ::: "memory");
  __builtin_amdgcn_s_waitcnt(0xC07F);
  __builtin_amdgcn_s_barrier();
  __asm__ __volatile__("" ::: "memory");
}

__device__ __forceinline__ short f2bf(float f) {  // fp32 -> bf16 RNE
  unsigned u = __float_as_uint(f);
  u = (u + 0x7FFF + ((u >> 16) & 1)) >> 16;
  return (short)u;
}

// lane-xor adds for k_scan reduction
__device__ __forceinline__ float add_xor1(float x) {
  int v = __builtin_amdgcn_mov_dpp(__float_as_int(x), 0xB1, 0xF, 0xF, true);
  return x + __int_as_float(v);
}
__device__ __forceinline__ float add_xor2(float x) {
  int v = __builtin_amdgcn_mov_dpp(__float_as_int(x), 0x4E, 0xF, 0xF, true);
  return x + __int_as_float(v);
}
__device__ __forceinline__ float add_xor4(float x) {
  int v = __builtin_amdgcn_ds_swizzle(__float_as_int(x), 0x101F);
  return x + __int_as_float(v);
}
__device__ __forceinline__ float dot4(float4 w, float4 h) {
  return fmaf(w.x, h.x, fmaf(w.y, h.y, fmaf(w.z, h.z, w.w * h.w)));
}

// ---------------------------------------------------------------------------
// Kernel 1: z = tanh(x @ Wx^T + bx) @ Wih^T + (bih + bhh)  (unchanged, fp32)
// ---------------------------------------------------------------------------
__global__ __launch_bounds__(256) void k_feat_z(
    const float* __restrict__ x,  const float* __restrict__ Wx,
    const float* __restrict__ bx, const float* __restrict__ Wih,
    const float* __restrict__ bih,const float* __restrict__ bhh,
    float* __restrict__ Z)
{
  __shared__ __align__(16) float lds[16384];
  float* xT    = lds;            // [64][68]
  float* WxT   = lds + 4352;     // [64][132]
  float* featT = lds;            // [128][68] (reuse)
  float* WT    = lds + 9216;     // [32][132]
  float* bxs   = lds + 16128;
  float* b2s   = lds + 16256;

  const int tid = threadIdx.x;
  const int r0  = blockIdx.x * 64;
  const int rg  = tid >> 4;
  const int cg  = tid & 15;

  if (tid < 128) { bxs[tid] = bx[tid]; b2s[tid] = bih[tid] + bhh[tid]; }

  {
    const float4* xg = (const float4*)(x + (long)r0 * D_IN);
#pragma unroll
    for (int k = 0; k < 4; ++k) {
      int l = tid + k * 256;
      float4 v = xg[l];
      int r = l >> 4, d0 = (l & 15) * 4;
      xT[(d0+0)*68 + r] = v.x; xT[(d0+1)*68 + r] = v.y;
      xT[(d0+2)*68 + r] = v.z; xT[(d0+3)*68 + r] = v.w;
    }
  }
  {
    const float4* wg = (const float4*)Wx;
#pragma unroll
    for (int k = 0; k < 8; ++k) {
      int l = tid + k * 256;
      float4 v = wg[l];
      int j = l >> 4, d0 = (l & 15) * 4;
      WxT[(d0+0)*132 + j] = v.x; WxT[(d0+1)*132 + j] = v.y;
      WxT[(d0+2)*132 + j] = v.z; WxT[(d0+3)*132 + j] = v.w;
    }
  }
  __syncthreads();

  float acc[4][8];
#pragma unroll
  for (int i = 0; i < 4; ++i)
#pragma unroll
    for (int c = 0; c < 8; ++c) acc[i][c] = 0.f;

  for (int d = 0; d < 64; ++d) {
    float4 xv = *(const float4*)&xT[d*68 + rg*4];
    float4 wa = *(const float4*)&WxT[d*132 + cg*8];
    float4 wb = *(const float4*)&WxT[d*132 + cg*8 + 4];
    float xr[4] = {xv.x, xv.y, xv.z, xv.w};
    float wc[8] = {wa.x, wa.y, wa.z, wa.w, wb.x, wb.y, wb.z, wb.w};
#pragma unroll
    for (int i = 0; i < 4; ++i)
#pragma unroll
      for (int c = 0; c < 8; ++c)
        acc[i][c] = fmaf(xr[i], wc[c], acc[i][c]);
  }
  __syncthreads();

#pragma unroll
  for (int c = 0; c < 8; ++c) {
    float bv = bxs[cg*8 + c];
#pragma unroll
    for (int i = 0; i < 4; ++i)
      featT[(cg*8+c)*68 + rg*4 + i] = fast_tanh(acc[i][c] + bv);
  }

  float acc2[4][8];
#pragma unroll
  for (int i = 0; i < 4; ++i)
#pragma unroll
    for (int c = 0; c < 8; ++c) acc2[i][c] = 0.f;

  for (int jc = 0; jc < 4; ++jc) {
    __syncthreads();
#pragma unroll
    for (int k = 0; k < 16; ++k) {
      int l = tid + k * 256;
      int o = l >> 5, jl = l & 31;
      WT[jl*132 + o] = Wih[o*128 + jc*32 + jl];
    }
    __syncthreads();
    for (int jl = 0; jl < 32; ++jl) {
      float4 fv = *(const float4*)&featT[(jc*32+jl)*68 + rg*4];
      float4 wa = *(const float4*)&WT[jl*132 + cg*8];
      float4 wb = *(const float4*)&WT[jl*132 + cg*8 + 4];
      float fr[4] = {fv.x, fv.y, fv.z, fv.w};
      float wc[8] = {wa.x, wa.y, wa.z, wa.w, wb.x, wb.y, wb.z, wb.w};
#pragma unroll
      for (int i = 0; i < 4; ++i)
#pragma unroll
        for (int c = 0; c < 8; ++c)
          acc2[i][c] = fmaf(fr[i], wc[c], acc2[i][c]);
    }
  }

#pragma unroll
  for (int i = 0; i < 4; ++i) {
    long r = r0 + rg*4 + i;
    float4 o1, o2;
    o1.x = acc2[i][0] + b2s[cg*8+0]; o1.y = acc2[i][1] + b2s[cg*8+1];
    o1.z = acc2[i][2] + b2s[cg*8+2]; o1.w = acc2[i][3] + b2s[cg*8+3];
    o2.x = acc2[i][4] + b2s[cg*8+4]; o2.y = acc2[i][5] + b2s[cg*8+5];
    o2.z = acc2[i][6] + b2s[cg*8+6]; o2.w = acc2[i][7] + b2s[cg*8+7];
    *(float4*)&Z[r*128 + cg*8]     = o1;
    *(float4*)&Z[r*128 + cg*8 + 4] = o2;
  }
}

// ---------------------------------------------------------------------------
// Kernel 2: recurrence. Same structure as R2 but in-loop barriers wait
// lgkmcnt ONLY -> the per-step global store + z-prefetch load no longer drain
// at every barrier (that vmcnt(0) drain was ~300+ cyc/step).
// ---------------------------------------------------------------------------
__global__ __launch_bounds__(256) void k_scan(const float* __restrict__ Whh,
                                              float* __restrict__ Z)
{
  __shared__ __align__(16) float hbuf[2][128];
  const int tid = threadIdx.x;
  const int b   = blockIdx.x;
  const int jg  = tid >> 3;      // 0..31
  const int ks  = tid & 7;       // 0..7
  const int k0  = ks * 16;

  float4 w[4][4];
#pragma unroll
  for (int r = 0; r < 4; ++r) {
    const float4* wg = (const float4*)(Whh + (jg + r*32)*H_DIM + k0);
#pragma unroll
    for (int m = 0; m < 4; ++m) w[r][m] = wg[m];
  }

  if (tid < 128) { hbuf[0][tid] = 0.f; }

  const bool writer = (ks < 4);
  const int  j_out  = jg + ks*32;
  float* zp = Z + b*H_DIM + j_out;

  float zbuf[8];
#pragma unroll
  for (int i = 0; i < 8; ++i) zbuf[i] = writer ? zp[i * 32768] : 0.f;

  barrier_lds_only();

  for (int tb = 0; tb < T_SEQ; tb += 8) {
#pragma unroll
    for (int u = 0; u < 8; ++u) {
      const int t = tb + u;
      const float* h = hbuf[t & 1];
      float4 h0 = *(const float4*)&h[k0];
      float4 h1 = *(const float4*)&h[k0 + 4];
      float4 h2 = *(const float4*)&h[k0 + 8];
      float4 h3 = *(const float4*)&h[k0 + 12];

      float a[4];
#pragma unroll
      for (int r = 0; r < 4; ++r) {
        float p0 = dot4(w[r][0], h0);
        float p1 = dot4(w[r][1], h1);
        float p2 = dot4(w[r][2], h2);
        float p3 = dot4(w[r][3], h3);
        a[r] = (p0 + p1) + (p2 + p3);
      }
#pragma unroll
      for (int r = 0; r < 4; ++r) {
        a[r] = add_xor1(a[r]);
        a[r] = add_xor2(a[r]);
        a[r] = add_xor4(a[r]);
      }
      if (writer) {
        float v  = a[ks] + zbuf[u];
        float hn = fast_tanh(v);
        hbuf[(t & 1) ^ 1][j_out] = hn;
        zp[t * 32768] = hn;
        zbuf[u] = (t + 8 < T_SEQ) ? zp[(t + 8) * 32768] : 0.f;
      }
      barrier_lds_only();
    }
  }
}

// ---------------------------------------------------------------------------
// Kernel 3 (REWRITTEN, bf16 MFMA): y = tanh(h Wh^T + bh) Wg^T + bg.
// 512 WGs x 8 tiles of 64 rows. Wh bf16 in LDS (stride 136 sh: 16B-aligned,
// uniform bank spread); Wg frags in registers; h staged bf16 per tile; m
// round-trips LDS in MFMA C-layout (col=lane&15, row=(lane>>4)*4+reg).
// ---------------------------------------------------------------------------
#define TILE_R 64
#define TPW    8
#define HM_S   136
#define WH_S   136

__global__ __launch_bounds__(256) void k_out_mfma(
    const float* __restrict__ Zh, const float* __restrict__ Wh,
    const float* __restrict__ bh, const float* __restrict__ Wg,
    const float* __restrict__ bg, float* __restrict__ y)
{
  __shared__ __align__(16) short wh_l[128 * WH_S];  // 34816 B
  __shared__ __align__(16) short hm_l[TILE_R * HM_S]; // 17408 B

  const int tid = threadIdx.x;
  const int l   = tid & 63;      // lane in wave
  const int wv  = tid >> 6;      // wave 0..3 -> rows [wv*16, wv*16+16)
  const int ln  = l & 15;        // m/n fragment index
  const int kg  = l >> 4;        // k-group 0..3

  // stage Wh -> LDS bf16 (once per WG)
  {
    const float4* wg4 = (const float4*)Wh;  // 128x128 = 4096 float4
#pragma unroll
    for (int p = 0; p < 16; ++p) {
      int f = tid + p * 256;
      int row = f >> 5, kc = (f & 31) * 4;
      float4 v = wg4[f];
      short4v s = { f2bf(v.x), f2bf(v.y), f2bf(v.z), f2bf(v.w) };
      *(short4v*)&wh_l[row * WH_S + kc] = s;
    }
  }

  // Wg fragments -> registers (B-layout: n = ln, k = kg*8 + j + 32*ks)
  short8 wg_r[4][4];
#pragma unroll
  for (int nt2 = 0; nt2 < 4; ++nt2)
#pragma unroll
    for (int ks = 0; ks < 4; ++ks) {
      const float* wp = Wg + (nt2*16 + ln) * H_DIM + ks*32 + kg*8;
      float4 a = *(const float4*)wp;
      float4 b = *(const float4*)(wp + 4);
      short8 s = { f2bf(a.x), f2bf(a.y), f2bf(a.z), f2bf(a.w),
                   f2bf(b.x), f2bf(b.y), f2bf(b.z), f2bf(b.w) };
      wg_r[nt2][ks] = s;
    }

  float bh_r[8], bg_r[4];
#pragma unroll
  for (int nt = 0; nt < 8; ++nt) bh_r[nt] = bh[nt*16 + ln];
#pragma unroll
  for (int nt2 = 0; nt2 < 4; ++nt2) bg_r[nt2] = bg[nt2*16 + ln];

  for (int it = 0; it < TPW; ++it) {
    const int tile = blockIdx.x * TPW + it;
    const long r0  = (long)tile * TILE_R;
    const bool zero = (tile < 4);        // rows < 256 -> t==0 -> h = 0

    // stage h tile (bf16) : 64 rows x 128 cols
    {
      const float4* hg = (const float4*)(Zh + (r0 - 256) * H_DIM);
#pragma unroll
      for (int p = 0; p < 8; ++p) {
        int f = tid + p * 256;           // 2048 float4 = 64x32
        int row = f >> 5, kc = (f & 31) * 4;
        float4 v;
        if (zero) { v.x = v.y = v.z = v.w = 0.f; } else { v = hg[f]; }
        short4v s = { f2bf(v.x), f2bf(v.y), f2bf(v.z), f2bf(v.w) };
        *(short4v*)&hm_l[row * HM_S + kc] = s;
      }
    }
    barrier_lds_only();

    // GEMM1: m = tanh(h @ Wh^T + bh), wave handles 16 rows
    short8 af[4];
#pragma unroll
    for (int ks = 0; ks < 4; ++ks)
      af[ks] = *(const short8*)&hm_l[(wv*16 + ln) * HM_S + ks*32 + kg*8];

#pragma unroll
    for (int nt = 0; nt < 8; ++nt) {
      f32x4 acc = {0.f, 0.f, 0.f, 0.f};
#pragma unroll
      for (int ks = 0; ks < 4; ++ks) {
        short8 bf = *(const short8*)&wh_l[(nt*16 + ln) * WH_S + ks*32 + kg*8];
        acc = __builtin_amdgcn_mfma_f32_16x16x32_bf16(af[ks], bf, acc, 0, 0, 0);
      }
#pragma unroll
      for (int c = 0; c < 4; ++c) {
        float val = fast_tanh(acc[c] + bh_r[nt]);
        hm_l[(wv*16 + kg*4 + c) * HM_S + nt*16 + ln] = f2bf(val);
      }
    }
    // same-wave LDS RAW: compiler inserts lgkmcnt wait

    // GEMM2: y = m @ Wg^T + bg
    short8 a2[4];
#pragma unroll
    for (int ks = 0; ks < 4; ++ks)
      a2[ks] = *(const short8*)&hm_l[(wv*16 + ln) * HM_S + ks*32 + kg*8];

#pragma unroll
    for (int nt2 = 0; nt2 < 4; ++nt2) {
      f32x4 acc2 = { bg_r[nt2], bg_r[nt2], bg_r[nt2], bg_r[nt2] };
#pragma unroll
      for (int ks = 0; ks < 4; ++ks)
        acc2 = __builtin_amdgcn_mfma_f32_16x16x32_bf16(a2[ks], wg_r[nt2][ks],
                                                       acc2, 0, 0, 0);
#pragma unroll
      for (int c = 0; c < 4; ++c)
        y[(r0 + wv*16 + kg*4 + c) * D_IN + nt2*16 + ln] = acc2[c];
    }
    barrier_lds_only();   // protect hm_l before next tile's staging
  }
}

extern "C" void kernel_launch(void* const* d_in, const int* in_sizes, int n_in,
                              void* d_out, int out_size, void* d_ws, size_t ws_size,
                              hipStream_t stream) {
  const float* x   = (const float*)d_in[0];
  const float* Wx  = (const float*)d_in[1];
  const float* bx  = (const float*)d_in[2];
  const float* Wih = (const float*)d_in[3];
  const float* bih = (const float*)d_in[4];
  const float* Whh = (const float*)d_in[5];
  const float* bhh = (const float*)d_in[6];
  const float* Wh  = (const float*)d_in[7];
  const float* bh  = (const float*)d_in[8];
  const float* Wg  = (const float*)d_in[9];
  const float* bg  = (const float*)d_in[10];
  float* Z = (float*)d_ws;              // T*B*H*4 = 134,217,728 B
  float* y = (float*)d_out;

  k_feat_z  <<<(T_SEQ * B_SZ) / 64, 256, 0, stream>>>(x, Wx, bx, Wih, bih, bhh, Z);
  k_scan    <<<B_SZ,               256, 0, stream>>>(Whh, Z);
  k_out_mfma<<<512,                256, 0, stream>>>(Z, Wh, bh, Wg, bg, y);
}